// Round 3
// baseline (153.023 us; speedup 1.0000x reference)
//
#include <hip/hip_runtime.h>

// Problem dims (static, match reference)
#define N_PIX (512*512)
#define NFEAT 8
#define NCLUS 8
#define NB    4
#define GRIDX 128                 // blocks per sample; 512 blocks total = 2/CU exact fit
#define NBLOCKS (GRIDX*NB)        // 512
#define NCHUNK (N_PIX/4)          // 65536 float4/int4 chunks per sample
#define STRIDE (GRIDX*256)        // 32768 -> compile-time 2 iterations/thread
#define NITER  (NCHUNK/STRIDE)    // 2
// Workspace layout (floats). Partials transposed for contiguous fold:
//   P[e][b][r] at e*512 + b*128 + r,  e in [0,72): 64 sums (f*8+c) + 8 counts
#define PART_TOTAL (72*NB*GRIDX)          // 36864
#define DIST_OFF  PART_TOTAL              // 512 per-block dist partials
#define S2_OFF    (DIST_OFF + NB*GRIDX)   // staged per-sample totals, stride 72
#define CTR_OFF   (S2_OFF + NB*72)        // 2 uint barrier counters (memset to 0)
// Every other ws location we read is written earlier in the same launch -> no
// init needed; safe against the harness 0xAA poison. Counters are memset.

// ---------------------------------------------------------------------------
// Software grid barrier (capturable — no cooperative launch needed).
// Release: __threadfence() flushes prior plain stores to the device coherence
// point (cross-XCD visible). Arrival: device-scope atomicAdd. Spin: relaxed
// agent-scope load. Acquire: __threadfence() invalidates stale L1/L2 lines.
// Co-residency of all 512 blocks is guaranteed by __launch_bounds__(256,2)
// (2 blocks/CU x 256 CUs == grid size), so the spin cannot deadlock; the
// guard bound (~4000x margin) turns any surprise into a wrong answer, not a
// hang.
// ---------------------------------------------------------------------------
__device__ __forceinline__ void grid_barrier(unsigned* ctr) {
    __syncthreads();
    if (threadIdx.x == 0) {
        __threadfence();   // release
        __hip_atomic_fetch_add(ctr, 1u, __ATOMIC_RELAXED, __HIP_MEMORY_SCOPE_AGENT);
        int guard = 0;
        while (__hip_atomic_load(ctr, __ATOMIC_RELAXED, __HIP_MEMORY_SCOPE_AGENT)
               < (unsigned)NBLOCKS) {
            if (++guard > (1 << 24)) break;   // safety valve: fail, don't hang
        }
        __threadfence();   // acquire
    }
    __syncthreads();
}

// ---------------------------------------------------------------------------
// Single fused kernel, 3 phases split by software grid barriers:
//   Phase A (= old k_sums): load each thread's 8 pixels ONCE into registers,
//     per-cluster select-FMA sums + ballot counts, 6-round reduce-scatter
//     butterfly, block fold via LDS, transposed partial store.
//   Phase B (= old k_var): fold partials -> means in LDS (stride-9 pad),
//     distance loop REUSES the register-held pixels (no second 37.7 MB read),
//     per-block dist partial store. bx==0 stages per-sample totals.
//   Phase C (= old k_final): block (0,0) only — validated epilogue math.
// All float summation orders identical to the 3-kernel version -> absmax 0.0.
// __launch_bounds__(256,2): <=256 VGPR, 2 blocks/CU so 512 blocks co-reside.
// ---------------------------------------------------------------------------
__global__ __launch_bounds__(256, 2) void k_fused(const float* __restrict__ pred,
                                                  const int* __restrict__ tgt,
                                                  float* __restrict__ ws,
                                                  float* __restrict__ out) {
    __shared__ float ssum[4][64];
    __shared__ float scnt[4][8];
    __shared__ float pp[72][4];
    __shared__ float raw[72];
    __shared__ float mean[NCLUS * 9];
    __shared__ float slv[4];
    __shared__ float sd[256];
    __shared__ float meanL[NB][64];
    __shared__ float slf[NB];

    const int tid = threadIdx.x;
    const int bx = blockIdx.x, b = blockIdx.y;
    const int lane = tid & 63, w = tid >> 6;
    unsigned* ctr = (unsigned*)(ws + CTR_OFF);

    const int4*   t4 = (const int4*)(tgt + b * N_PIX);
    const float4* p4 = (const float4*)(pred + (size_t)b * NFEAT * N_PIX);

    // ---- load this thread's pixels ONCE; keep resident in VGPRs ----
    int   gss[NITER][4];
    float prs[NITER][NFEAT][4];
#pragma unroll
    for (int it = 0; it < NITER; ++it) {
        const int i = bx * 256 + tid + it * STRIDE;
        int4 g4 = t4[i];
        gss[it][0] = g4.x; gss[it][1] = g4.y; gss[it][2] = g4.z; gss[it][3] = g4.w;
#pragma unroll
        for (int f = 0; f < NFEAT; ++f) {
            float4 v = p4[f * NCHUNK + i];
            prs[it][f][0] = v.x; prs[it][f][1] = v.y;
            prs[it][f][2] = v.z; prs[it][f][3] = v.w;
        }
    }

    // ---- Phase A: per-cluster feature sums + counts (order == old k_sums) --
    float acc[64];
#pragma unroll
    for (int i = 0; i < 64; ++i) acc[i] = 0.0f;
    int cnt[8] = {0, 0, 0, 0, 0, 0, 0, 0};

#pragma unroll
    for (int it = 0; it < NITER; ++it) {
#pragma unroll
        for (int j = 0; j < 4; ++j) {
            float m[NCLUS];
#pragma unroll
            for (int c = 0; c < NCLUS; ++c) {
                bool hit = (gss[it][j] == c);
                m[c] = hit ? 1.0f : 0.0f;
                cnt[c] += (int)__popcll(__ballot(hit));
            }
#pragma unroll
            for (int f = 0; f < NFEAT; ++f)
#pragma unroll
                for (int c = 0; c < NCLUS; ++c)
                    acc[f * 8 + c] = fmaf(m[c], prs[it][f][j], acc[f * 8 + c]);
        }
    }

    // Reduce-scatter butterfly: after 6 rounds acc[0] = wave total of entry
    // 'lane'.
#pragma unroll
    for (int k = 0; k < 6; ++k) {
        const int d = 1 << k;
        const int bit = (lane >> k) & 1;
#pragma unroll
        for (int p = 0; p < (64 >> 1); ++p) {
            if (p >= (64 >> (k + 1))) break;
            float a  = __shfl_xor(acc[2 * p],     d, 64);
            float vb = __shfl_xor(acc[2 * p + 1], d, 64);
            float own = bit ? acc[2 * p + 1] : acc[2 * p];
            float oth = bit ? vb : a;
            acc[p] = own + oth;
        }
    }

    ssum[w][lane] = acc[0];
    if (lane == 0) {
#pragma unroll
        for (int c = 0; c < NCLUS; ++c) scnt[w][c] = (float)cnt[c];
    }
    __syncthreads();
    if (tid < 72) {
        float s;
        if (tid < 64) s = ssum[0][tid] + ssum[1][tid] + ssum[2][tid] + ssum[3][tid];
        else { int c2 = tid - 64; s = scnt[0][c2] + scnt[1][c2] + scnt[2][c2] + scnt[3][c2]; }
        ws[tid * (NB * GRIDX) + b * GRIDX + bx] = s;   // transposed plain store
    }

    grid_barrier(ctr + 0);   // partials from all blocks/XCDs visible

    // ---- Phase B: fold partials -> means; distance from register pixels ----
    for (int s = tid; s < 288; s += 256) {
        const int e = s >> 2, q = s & 3;
        const float4* src = (const float4*)(ws + e * (NB * GRIDX) + b * GRIDX) + q * 8;
        float4 a0 = src[0], a1 = src[1], a2 = src[2], a3 = src[3];
        float4 a4 = src[4], a5 = src[5], a6 = src[6], a7 = src[7];
        float r0 = (a0.x + a0.y + a0.z + a0.w) + (a1.x + a1.y + a1.z + a1.w);
        float r1 = (a2.x + a2.y + a2.z + a2.w) + (a3.x + a3.y + a3.z + a3.w);
        float r2 = (a4.x + a4.y + a4.z + a4.w) + (a5.x + a5.y + a5.z + a5.w);
        float r3 = (a6.x + a6.y + a6.z + a6.w) + (a7.x + a7.y + a7.z + a7.w);
        pp[e][q] = (r0 + r1) + (r2 + r3);
    }
    __syncthreads();
    if (tid < 72) {
        float s = (pp[tid][0] + pp[tid][1]) + (pp[tid][2] + pp[tid][3]);
        raw[tid] = s;
        if (bx == 0) ws[S2_OFF + b * 72 + tid] = s;   // stage for Phase C
    }
    __syncthreads();
    if (tid < 64) {
        const int f = tid >> 3, c = tid & 7;
        mean[c * 9 + f] = raw[f * 8 + c] / raw[64 + c];   // stride-9: conflict-free
    }
    __syncthreads();

    float local = 0.0f;
#pragma unroll
    for (int it = 0; it < NITER; ++it) {
#pragma unroll
        for (int j = 0; j < 4; ++j) {
            const float* mm = &mean[gss[it][j] * 9];
            float dsq = 0.0f;
#pragma unroll
            for (int f = 0; f < NFEAT; ++f) {
                float d = mm[f] - prs[it][f][j];
                dsq = fmaf(d, d, dsq);
            }
            float diff = sqrtf(dsq);
            float dm = fminf(fmaxf(diff - 0.5f, 0.0f), 100000.0f);
            local = fmaf(dm, dm, local);
        }
    }

#pragma unroll
    for (int o = 32; o >= 1; o >>= 1) local += __shfl_xor(local, o, 64);
    if ((tid & 63) == 0) slv[tid >> 6] = local;
    __syncthreads();
    if (tid == 0)
        ws[DIST_OFF + bx * NB + b] = slv[0] + slv[1] + slv[2] + slv[3];  // plain store

    grid_barrier(ctr + 1);   // dist partials + S2 stage visible

    // ---- Phase C: epilogue on block (0,0) only (math == old k_final) ------
    if (bx != 0 || b != 0) return;

    sd[tid] = ws[DIST_OFF + tid] + ws[DIST_OFF + 256 + tid];
    __syncthreads();
#pragma unroll
    for (int off = 128; off >= 4; off >>= 1) {
        if (tid < off) sd[tid] += sd[tid + off];
        __syncthreads();
    }
    // sd[0..3] = per-sample dist totals (index mod 4 == b preserved)

    const int bb = tid >> 6, idx = tid & 63;
    const float* S2 = ws + S2_OFF + bb * 72;
    meanL[bb][idx] = S2[idx] / S2[64 + (idx & 7)];
    __syncthreads();

    const int ii = idx >> 3, jj = idx & 7;
    float pdsq = 0.0f;
#pragma unroll
    for (int f = 0; f < 8; ++f) {
        float d = meanL[bb][f * 8 + ii] - meanL[bb][f * 8 + jj];
        pdsq = fmaf(d, d, pdsq);
    }
    float nrm = sqrtf(pdsq);
    float t = fminf(fmaxf(3.0f - nrm, 0.0f), 100000.0f);   // margin = 2*delta_d
    float val = (ii == jj) ? 0.0f : t * t * (1.0f / 56.0f); // / (C*(C-1))

    if (ii == 0) {
        float rsq = 0.0f;
#pragma unroll
        for (int f = 0; f < 8; ++f) {
            float m2 = meanL[bb][f * 8 + jj];
            rsq = fmaf(m2, m2, rsq);
        }
        float invc = 1.0f / S2[64 + jj];
        val += 0.001f * sqrtf(rsq) * 0.125f + sd[bb] * invc * 0.125f;
    }

#pragma unroll
    for (int o = 32; o >= 1; o >>= 1) val += __shfl_xor(val, o, 64);
    if (idx == 0) slf[bb] = val;
    __syncthreads();
    if (tid == 0) out[0] = (slf[0] + slf[1] + slf[2] + slf[3]) * 0.25f;
}

// ---------------------------------------------------------------------------
extern "C" void kernel_launch(void* const* d_in, const int* in_sizes, int n_in,
                              void* d_out, int out_size, void* d_ws, size_t ws_size,
                              hipStream_t stream) {
    const float* pred = (const float*)d_in[0];
    const int*   tgt  = (const int*)d_in[1];
    float* out = (float*)d_out;
    float* ws  = (float*)d_ws;

    // Zero the 2 barrier counters (ws is 0xAA-poisoned each iteration).
    // hipMemsetAsync is graph-capture-safe.
    hipMemsetAsync((char*)d_ws + (size_t)CTR_OFF * sizeof(float), 0, 8, stream);

    dim3 grid(GRIDX, NB);   // 512 blocks = 2/CU exact co-residency
    k_fused<<<grid, 256, 0, stream>>>(pred, tgt, ws, out);
}

// Round 4
// 118.738 us; speedup vs baseline: 1.2887x; 1.2887x over previous
//
#include <hip/hip_runtime.h>

// Problem dims (static, match reference)
#define N_PIX (512*512)
#define NFEAT 8
#define NCLUS 8
#define NB    4
#define GRIDX 128                 // blocks per sample; 512 blocks total = 2/CU exact fit
#define NBLOCKS (GRIDX*NB)        // 512
#define NCHUNK (N_PIX/4)          // 65536 float4/int4 chunks per sample
#define STRIDE (GRIDX*256)        // 32768 -> compile-time 2 iterations/thread
#define NITER  (NCHUNK/STRIDE)    // 2
// Workspace layout (floats). Partials transposed for contiguous fold:
//   P[e][b][r] at e*512 + b*128 + r,  e in [0,72): 64 sums (f*8+c) + 8 counts
#define PART_TOTAL (72*NB*GRIDX)          // 36864
#define DIST_OFF  PART_TOTAL              // 512 per-block dist partials
#define S2_OFF    (DIST_OFF + NB*GRIDX)   // staged per-sample totals, stride 72
#define CTR_OFF   (S2_OFF + NB*72)        // 2 uint counters (memset to 0 each call)

// ---------------------------------------------------------------------------
// Cross-block data protocol (NO __threadfence -> no buffer_wbl2/buffer_inv):
// all values that cross a block boundary are written with agent-scope RELAXED
// atomic stores (write-through to the device coherence point) and read with
// agent-scope RELAXED atomic loads (bypass possibly-stale L1/per-XCD L2).
// __syncthreads() drains each wave's outstanding stores (compiler emits
// s_waitcnt vmcnt(0) before s_barrier), so by the time thread 0 increments the
// arrival counter, the whole block's published data is globally visible.
// Round-3 lesson: __threadfence() per block per barrier (1024 full L2
// writeback+invalidates) + backoff-free spin = 95% stall, 99 us kernel.
// ---------------------------------------------------------------------------
__device__ __forceinline__ void agent_st(float* p, float v) {
    __hip_atomic_store(p, v, __ATOMIC_RELAXED, __HIP_MEMORY_SCOPE_AGENT);
}
__device__ __forceinline__ float agent_ld(const float* p) {
    return __hip_atomic_load((float*)p, __ATOMIC_RELAXED, __HIP_MEMORY_SCOPE_AGENT);
}

// ---------------------------------------------------------------------------
// Single fused kernel:
//   Phase A (= old k_sums): load each thread's 8 pixels ONCE into registers,
//     per-cluster select-FMA sums + ballot counts, butterfly, block fold,
//     transposed partial store (agent-scope).
//   -- spin grid barrier (s_sleep backoff, co-residency by launch_bounds) --
//   Phase B (= old k_var): fold partials -> means in LDS, distance loop
//     REUSES register-held pixels (no second 37.7 MB read), dist partial
//     store (agent-scope).
//   -- arrival counter: LAST block (fetch_add returns 511) runs Phase C,
//      everyone else exits. No second spin. --
//   Phase C (= old k_final): validated epilogue math.
// All float summation orders identical to the 3-kernel version -> absmax 0.0.
// __launch_bounds__(256,2): 2 blocks/CU x 256 CUs == 512-block grid, so the
// spin barrier cannot deadlock; guard bound fails loudly instead of hanging.
// ---------------------------------------------------------------------------
__global__ __launch_bounds__(256, 2) void k_fused(const float* __restrict__ pred,
                                                  const int* __restrict__ tgt,
                                                  float* __restrict__ ws,
                                                  float* __restrict__ out) {
    __shared__ float ssum[4][64];
    __shared__ float scnt[4][8];
    __shared__ float pp[72][4];
    __shared__ float raw[72];
    __shared__ float mean[NCLUS * 9];
    __shared__ float slv[4];
    __shared__ int   is_last;
    __shared__ float sd[256];
    __shared__ float meanL[NB][64];
    __shared__ float slf[NB];

    const int tid = threadIdx.x;
    const int bx = blockIdx.x, b = blockIdx.y;
    const int lane = tid & 63, w = tid >> 6;
    unsigned* ctr = (unsigned*)(ws + CTR_OFF);

    const int4*   t4 = (const int4*)(tgt + b * N_PIX);
    const float4* p4 = (const float4*)(pred + (size_t)b * NFEAT * N_PIX);

    // ---- load this thread's pixels ONCE; keep resident in VGPRs/AGPRs ----
    int   gss[NITER][4];
    float prs[NITER][NFEAT][4];
#pragma unroll
    for (int it = 0; it < NITER; ++it) {
        const int i = bx * 256 + tid + it * STRIDE;
        int4 g4 = t4[i];
        gss[it][0] = g4.x; gss[it][1] = g4.y; gss[it][2] = g4.z; gss[it][3] = g4.w;
#pragma unroll
        for (int f = 0; f < NFEAT; ++f) {
            float4 v = p4[f * NCHUNK + i];
            prs[it][f][0] = v.x; prs[it][f][1] = v.y;
            prs[it][f][2] = v.z; prs[it][f][3] = v.w;
        }
    }

    // ---- Phase A: per-cluster feature sums + counts (order == old k_sums) --
    float acc[64];
#pragma unroll
    for (int i = 0; i < 64; ++i) acc[i] = 0.0f;
    int cnt[8] = {0, 0, 0, 0, 0, 0, 0, 0};

#pragma unroll
    for (int it = 0; it < NITER; ++it) {
#pragma unroll
        for (int j = 0; j < 4; ++j) {
            float m[NCLUS];
#pragma unroll
            for (int c = 0; c < NCLUS; ++c) {
                bool hit = (gss[it][j] == c);
                m[c] = hit ? 1.0f : 0.0f;
                cnt[c] += (int)__popcll(__ballot(hit));
            }
#pragma unroll
            for (int f = 0; f < NFEAT; ++f)
#pragma unroll
                for (int c = 0; c < NCLUS; ++c)
                    acc[f * 8 + c] = fmaf(m[c], prs[it][f][j], acc[f * 8 + c]);
        }
    }

    // Reduce-scatter butterfly: after 6 rounds acc[0] = wave total of entry
    // 'lane'.
#pragma unroll
    for (int k = 0; k < 6; ++k) {
        const int d = 1 << k;
        const int bit = (lane >> k) & 1;
#pragma unroll
        for (int p = 0; p < (64 >> 1); ++p) {
            if (p >= (64 >> (k + 1))) break;
            float a  = __shfl_xor(acc[2 * p],     d, 64);
            float vb = __shfl_xor(acc[2 * p + 1], d, 64);
            float own = bit ? acc[2 * p + 1] : acc[2 * p];
            float oth = bit ? vb : a;
            acc[p] = own + oth;
        }
    }

    ssum[w][lane] = acc[0];
    if (lane == 0) {
#pragma unroll
        for (int c = 0; c < NCLUS; ++c) scnt[w][c] = (float)cnt[c];
    }
    __syncthreads();
    if (tid < 72) {
        float s;
        if (tid < 64) s = ssum[0][tid] + ssum[1][tid] + ssum[2][tid] + ssum[3][tid];
        else { int c2 = tid - 64; s = scnt[0][c2] + scnt[1][c2] + scnt[2][c2] + scnt[3][c2]; }
        agent_st(&ws[tid * (NB * GRIDX) + b * GRIDX + bx], s);  // coherent store
    }
    __syncthreads();   // drains every wave's stores -> block's data visible

    // ---- spin grid barrier (only thread 0 spins, s_sleep backoff) ----
    if (tid == 0) {
        asm volatile("s_waitcnt vmcnt(0)" ::: "memory");
        __hip_atomic_fetch_add(ctr, 1u, __ATOMIC_RELAXED, __HIP_MEMORY_SCOPE_AGENT);
        int guard = 0;
        for (;;) {
            unsigned v = __hip_atomic_load(ctr, __ATOMIC_RELAXED,
                                           __HIP_MEMORY_SCOPE_AGENT);
            if (v >= (unsigned)NBLOCKS) break;
            __builtin_amdgcn_s_sleep(8);          // ~512 cy backoff per poll
            if (++guard > (1 << 20)) break;       // fail loudly, never hang
        }
    }
    __syncthreads();

    // ---- Phase B: fold partials -> means; distance from register pixels ----
    // (scalar agent loads; association tree identical to old float4 fold)
    for (int s = tid; s < 288; s += 256) {
        const int e = s >> 2, q = s & 3;
        const float* src = ws + e * (NB * GRIDX) + b * GRIDX + q * 32;
        float t[32];
#pragma unroll
        for (int k2 = 0; k2 < 32; ++k2) t[k2] = agent_ld(src + k2);
        float u[8];
#pragma unroll
        for (int k2 = 0; k2 < 8; ++k2)
            u[k2] = ((t[4 * k2] + t[4 * k2 + 1]) + t[4 * k2 + 2]) + t[4 * k2 + 3];
        float r0 = u[0] + u[1], r1 = u[2] + u[3];
        float r2 = u[4] + u[5], r3 = u[6] + u[7];
        pp[e][q] = (r0 + r1) + (r2 + r3);
    }
    __syncthreads();
    if (tid < 72) {
        float s = (pp[tid][0] + pp[tid][1]) + (pp[tid][2] + pp[tid][3]);
        raw[tid] = s;
        if (bx == 0) agent_st(&ws[S2_OFF + b * 72 + tid], s);   // stage for Phase C
    }
    __syncthreads();
    if (tid < 64) {
        const int f = tid >> 3, c = tid & 7;
        mean[c * 9 + f] = raw[f * 8 + c] / raw[64 + c];   // stride-9: conflict-free
    }
    __syncthreads();

    float local = 0.0f;
#pragma unroll
    for (int it = 0; it < NITER; ++it) {
#pragma unroll
        for (int j = 0; j < 4; ++j) {
            const float* mm = &mean[gss[it][j] * 9];
            float dsq = 0.0f;
#pragma unroll
            for (int f = 0; f < NFEAT; ++f) {
                float d = mm[f] - prs[it][f][j];
                dsq = fmaf(d, d, dsq);
            }
            float diff = sqrtf(dsq);
            float dm = fminf(fmaxf(diff - 0.5f, 0.0f), 100000.0f);
            local = fmaf(dm, dm, local);
        }
    }

#pragma unroll
    for (int o = 32; o >= 1; o >>= 1) local += __shfl_xor(local, o, 64);
    if ((tid & 63) == 0) slv[tid >> 6] = local;
    __syncthreads();

    // ---- arrival: LAST block to finish Phase B runs Phase C; rest exit ----
    if (tid == 0) {
        agent_st(&ws[DIST_OFF + bx * NB + b], slv[0] + slv[1] + slv[2] + slv[3]);
        asm volatile("s_waitcnt vmcnt(0)" ::: "memory");
        unsigned old = __hip_atomic_fetch_add(ctr + 1, 1u, __ATOMIC_RELAXED,
                                              __HIP_MEMORY_SCOPE_AGENT);
        is_last = (old == (unsigned)(NBLOCKS - 1));
    }
    __syncthreads();
    if (!is_last) return;

    // ---- Phase C: epilogue, executed by the single last block -------------
    sd[tid] = agent_ld(ws + DIST_OFF + tid) + agent_ld(ws + DIST_OFF + 256 + tid);
    __syncthreads();
#pragma unroll
    for (int off = 128; off >= 4; off >>= 1) {
        if (tid < off) sd[tid] += sd[tid + off];
        __syncthreads();
    }
    // sd[0..3] = per-sample dist totals (index mod 4 == b preserved)

    const int bb = tid >> 6, idx = tid & 63;
    const float* S2 = ws + S2_OFF + bb * 72;
    meanL[bb][idx] = agent_ld(S2 + idx) / agent_ld(S2 + 64 + (idx & 7));
    __syncthreads();

    const int ii = idx >> 3, jj = idx & 7;
    float pdsq = 0.0f;
#pragma unroll
    for (int f = 0; f < 8; ++f) {
        float d = meanL[bb][f * 8 + ii] - meanL[bb][f * 8 + jj];
        pdsq = fmaf(d, d, pdsq);
    }
    float nrm = sqrtf(pdsq);
    float t = fminf(fmaxf(3.0f - nrm, 0.0f), 100000.0f);   // margin = 2*delta_d
    float val = (ii == jj) ? 0.0f : t * t * (1.0f / 56.0f); // / (C*(C-1))

    if (ii == 0) {
        float rsq = 0.0f;
#pragma unroll
        for (int f = 0; f < 8; ++f) {
            float m2 = meanL[bb][f * 8 + jj];
            rsq = fmaf(m2, m2, rsq);
        }
        float invc = 1.0f / agent_ld(S2 + 64 + jj);
        val += 0.001f * sqrtf(rsq) * 0.125f + sd[bb] * invc * 0.125f;
    }

#pragma unroll
    for (int o = 32; o >= 1; o >>= 1) val += __shfl_xor(val, o, 64);
    if (idx == 0) slf[bb] = val;
    __syncthreads();
    if (tid == 0) out[0] = (slf[0] + slf[1] + slf[2] + slf[3]) * 0.25f;
}

// ---------------------------------------------------------------------------
extern "C" void kernel_launch(void* const* d_in, const int* in_sizes, int n_in,
                              void* d_out, int out_size, void* d_ws, size_t ws_size,
                              hipStream_t stream) {
    const float* pred = (const float*)d_in[0];
    const int*   tgt  = (const int*)d_in[1];
    float* out = (float*)d_out;
    float* ws  = (float*)d_ws;

    // Zero the 2 counters (ws is 0xAA-poisoned each iteration). Capturable.
    hipMemsetAsync((char*)d_ws + (size_t)CTR_OFF * sizeof(float), 0, 8, stream);

    dim3 grid(GRIDX, NB);   // 512 blocks = 2/CU exact co-residency
    k_fused<<<grid, 256, 0, stream>>>(pred, tgt, ws, out);
}

// Round 5
// 94.246 us; speedup vs baseline: 1.6236x; 1.2599x over previous
//
#include <hip/hip_runtime.h>

// Problem dims (static, match reference)
#define N_PIX (512*512)
#define NFEAT 8
#define NCLUS 8
#define NB    4
#define GRIDX 128                 // blocks per sample; 512 blocks total = 2/CU exact fit
#define NBLOCKS (GRIDX*NB)        // 512
#define NCHUNK (N_PIX/4)          // 65536 float4/int4 chunks per sample
#define STRIDE (GRIDX*256)        // 32768 -> compile-time 2 iterations/thread
#define NITER  (NCHUNK/STRIDE)    // 2

// Workspace layout (floats). Round-4 lesson: per-block partials refolded by
// every block as uncached scalar loads = 4.7M coherence-point transactions
// = 19.1 MB FETCH = 52 of the 56 us. Replaced by atomic totals: each entry
// padded to its own 64-B line so the ~512 adds per entry serialize on
// independent lines (~1 us), not 5 shared lines.
#define PAD 16                            // floats per entry = one 64-B line
#define TOT_OFF  0                        // totals[b][e] : b*72*PAD + e*PAD
                                          //   e<64: feature sums (f*8+c); 64..71: counts
#define TOT_SZ   (NB*72*PAD)              // 4608 floats
#define DIST_OFF TOT_SZ                   // dist[b] : DIST_OFF + b*PAD
#define DIST_SZ  (NB*PAD)                 // 64 floats
#define CTR_OFF  (DIST_OFF + DIST_SZ)     // uint counters: [b]*PAD arrival, [4]*PAD final
#define CLEAR_FLOATS (CTR_OFF + 5*PAD)    // 4752 floats = 19 KB memset region

// Agent-scope (device-coherent) primitives. NO __threadfence anywhere ->
// no buffer_wbl2/buffer_inv storms (round-3 lesson: those cost 43 us).
// Counts are integer-valued float sums < 2^24 -> exact under any add order;
// feature sums wobble in the last bit (absmax ~1e-5 << 1.06 threshold).
__device__ __forceinline__ float agent_ld(const float* p) {
    return __hip_atomic_load((float*)p, __ATOMIC_RELAXED, __HIP_MEMORY_SCOPE_AGENT);
}
__device__ __forceinline__ void agent_add(float* p, float v) {
    __hip_atomic_fetch_add(p, v, __ATOMIC_RELAXED, __HIP_MEMORY_SCOPE_AGENT);
}

// ---------------------------------------------------------------------------
// Single fused kernel:
//   Phase A: load each thread's 8 pixels, per-cluster select-FMA sums +
//     ballot counts, butterfly, block fold in LDS, then 72 atomicAdds into
//     the per-sample totals (one padded line each).
//   -- per-SAMPLE spin barrier (128 arrivals; co-residency by launch_bounds;
//      __syncthreads before arrival drains vmcnt -> data adds visible) --
//   Phase B: read 72 totals (uncached), means in LDS, distance loop
//     (pred re-read is L1/L2-warm), one atomicAdd of the block's dist
//     partial, last-block election via final counter.
//   Phase C: the single last block computes l_dist/l_reg/l_var-quirk from
//     the totals + dist sums and writes the scalar output.
// __launch_bounds__(256,2): 2 blocks/CU x 256 CUs == 512-block grid, so the
// spin barrier cannot deadlock; guard bound fails loudly instead of hanging.
// ---------------------------------------------------------------------------
__global__ __launch_bounds__(256, 2) void k_fused(const float* __restrict__ pred,
                                                  const int* __restrict__ tgt,
                                                  float* __restrict__ ws,
                                                  float* __restrict__ out) {
    __shared__ float ssum[4][64];
    __shared__ float scnt[4][8];
    __shared__ float raw[72];
    __shared__ float mean[NCLUS * 9];
    __shared__ float slv[4];
    __shared__ int   is_last;
    __shared__ float meanL[NB][64];
    __shared__ float slf[NB];

    const int tid = threadIdx.x;
    const int bx = blockIdx.x, b = blockIdx.y;
    const int lane = tid & 63, w = tid >> 6;
    unsigned* ctr = (unsigned*)(ws + CTR_OFF);
    float* tot = ws + TOT_OFF + b * 72 * PAD;

    const int4*   t4 = (const int4*)(tgt + b * N_PIX);
    const float4* p4 = (const float4*)(pred + (size_t)b * NFEAT * N_PIX);

    // ---- load this thread's pixels ----
    int   gss[NITER][4];
    float prs[NITER][NFEAT][4];
#pragma unroll
    for (int it = 0; it < NITER; ++it) {
        const int i = bx * 256 + tid + it * STRIDE;
        int4 g4 = t4[i];
        gss[it][0] = g4.x; gss[it][1] = g4.y; gss[it][2] = g4.z; gss[it][3] = g4.w;
#pragma unroll
        for (int f = 0; f < NFEAT; ++f) {
            float4 v = p4[f * NCHUNK + i];
            prs[it][f][0] = v.x; prs[it][f][1] = v.y;
            prs[it][f][2] = v.z; prs[it][f][3] = v.w;
        }
    }

    // ---- Phase A: per-cluster feature sums + counts ----
    float acc[64];
#pragma unroll
    for (int i = 0; i < 64; ++i) acc[i] = 0.0f;
    int cnt[8] = {0, 0, 0, 0, 0, 0, 0, 0};

#pragma unroll
    for (int it = 0; it < NITER; ++it) {
#pragma unroll
        for (int j = 0; j < 4; ++j) {
            float m[NCLUS];
#pragma unroll
            for (int c = 0; c < NCLUS; ++c) {
                bool hit = (gss[it][j] == c);
                m[c] = hit ? 1.0f : 0.0f;
                cnt[c] += (int)__popcll(__ballot(hit));
            }
#pragma unroll
            for (int f = 0; f < NFEAT; ++f)
#pragma unroll
                for (int c = 0; c < NCLUS; ++c)
                    acc[f * 8 + c] = fmaf(m[c], prs[it][f][j], acc[f * 8 + c]);
        }
    }

    // Reduce-scatter butterfly: acc[0] = wave total of entry 'lane'.
#pragma unroll
    for (int k = 0; k < 6; ++k) {
        const int d = 1 << k;
        const int bit = (lane >> k) & 1;
#pragma unroll
        for (int p = 0; p < (64 >> 1); ++p) {
            if (p >= (64 >> (k + 1))) break;
            float a  = __shfl_xor(acc[2 * p],     d, 64);
            float vb = __shfl_xor(acc[2 * p + 1], d, 64);
            float own = bit ? acc[2 * p + 1] : acc[2 * p];
            float oth = bit ? vb : a;
            acc[p] = own + oth;
        }
    }

    ssum[w][lane] = acc[0];
    if (lane == 0) {
#pragma unroll
        for (int c = 0; c < NCLUS; ++c) scnt[w][c] = (float)cnt[c];
    }
    __syncthreads();
    if (tid < 72) {
        float s;
        if (tid < 64) s = ssum[0][tid] + ssum[1][tid] + ssum[2][tid] + ssum[3][tid];
        else { int c2 = tid - 64; s = scnt[0][c2] + scnt[1][c2] + scnt[2][c2] + scnt[3][c2]; }
        agent_add(&tot[tid * PAD], s);     // one padded line per entry
    }
    __syncthreads();   // compiler drains vmcnt before s_barrier -> adds visible

    // ---- per-sample spin barrier (only thread 0 spins, s_sleep backoff) ----
    if (tid == 0) {
        __hip_atomic_fetch_add(&ctr[b * PAD], 1u, __ATOMIC_RELAXED,
                               __HIP_MEMORY_SCOPE_AGENT);
        int guard = 0;
        for (;;) {
            unsigned v = __hip_atomic_load(&ctr[b * PAD], __ATOMIC_RELAXED,
                                           __HIP_MEMORY_SCOPE_AGENT);
            if (v >= (unsigned)GRIDX) break;
            __builtin_amdgcn_s_sleep(2);          // ~128 cy backoff per poll
            if (++guard > (1 << 20)) break;       // fail loudly, never hang
        }
    }
    __syncthreads();

    // ---- Phase B: totals -> means; distance loop ----
    if (tid < 72) raw[tid] = agent_ld(&tot[tid * PAD]);   // 72 loads/block only
    __syncthreads();
    if (tid < 64) {
        const int f = tid >> 3, c = tid & 7;
        mean[c * 9 + f] = raw[f * 8 + c] / raw[64 + c];   // stride-9: conflict-free
    }
    __syncthreads();

    float local = 0.0f;
#pragma unroll
    for (int it = 0; it < NITER; ++it) {
#pragma unroll
        for (int j = 0; j < 4; ++j) {
            const float* mm = &mean[gss[it][j] * 9];
            float dsq = 0.0f;
#pragma unroll
            for (int f = 0; f < NFEAT; ++f) {
                float d = mm[f] - prs[it][f][j];
                dsq = fmaf(d, d, dsq);
            }
            float diff = sqrtf(dsq);
            float dm = fminf(fmaxf(diff - 0.5f, 0.0f), 100000.0f);
            local = fmaf(dm, dm, local);
        }
    }

#pragma unroll
    for (int o = 32; o >= 1; o >>= 1) local += __shfl_xor(local, o, 64);
    if ((tid & 63) == 0) slv[tid >> 6] = local;
    __syncthreads();

    // ---- dist atomicAdd + last-block election (no second spin) ----
    if (tid == 0) {
        agent_add(&ws[DIST_OFF + b * PAD], slv[0] + slv[1] + slv[2] + slv[3]);
        asm volatile("s_waitcnt vmcnt(0)" ::: "memory");  // dist add visible first
        unsigned old = __hip_atomic_fetch_add(&ctr[4 * PAD], 1u, __ATOMIC_RELAXED,
                                              __HIP_MEMORY_SCOPE_AGENT);
        is_last = (old == (unsigned)(NBLOCKS - 1));
    }
    __syncthreads();
    if (!is_last) return;

    // ---- Phase C: epilogue, executed by the single last block -------------
    const int bb = tid >> 6, idx = tid & 63;
    const float* T = ws + TOT_OFF + bb * 72 * PAD;
    meanL[bb][idx] = agent_ld(&T[idx * PAD]) / agent_ld(&T[(64 + (idx & 7)) * PAD]);
    __syncthreads();

    const int ii = idx >> 3, jj = idx & 7;
    float pdsq = 0.0f;
#pragma unroll
    for (int f = 0; f < 8; ++f) {
        float d = meanL[bb][f * 8 + ii] - meanL[bb][f * 8 + jj];
        pdsq = fmaf(d, d, pdsq);
    }
    float nrm = sqrtf(pdsq);
    float t = fminf(fmaxf(3.0f - nrm, 0.0f), 100000.0f);   // margin = 2*delta_d
    float val = (ii == jj) ? 0.0f : t * t * (1.0f / 56.0f); // / (C*(C-1))

    if (ii == 0) {
        float rsq = 0.0f;
#pragma unroll
        for (int f = 0; f < 8; ++f) {
            float m2 = meanL[bb][f * 8 + jj];
            rsq = fmaf(m2, m2, rsq);
        }
        float invc = 1.0f / agent_ld(&T[(64 + jj) * PAD]);
        float dtot = agent_ld(&ws[DIST_OFF + bb * PAD]);
        val += 0.001f * sqrtf(rsq) * 0.125f + dtot * invc * 0.125f;
    }

#pragma unroll
    for (int o = 32; o >= 1; o >>= 1) val += __shfl_xor(val, o, 64);
    if (idx == 0) slf[bb] = val;
    __syncthreads();
    if (tid == 0) out[0] = (slf[0] + slf[1] + slf[2] + slf[3]) * 0.25f;
}

// ---------------------------------------------------------------------------
extern "C" void kernel_launch(void* const* d_in, const int* in_sizes, int n_in,
                              void* d_out, int out_size, void* d_ws, size_t ws_size,
                              hipStream_t stream) {
    const float* pred = (const float*)d_in[0];
    const int*   tgt  = (const int*)d_in[1];
    float* out = (float*)d_out;
    float* ws  = (float*)d_ws;

    // Zero totals + dist + counters (ws is poisoned each iteration). One
    // 19 KB capturable memset node.
    hipMemsetAsync(d_ws, 0, CLEAR_FLOATS * sizeof(float), stream);

    dim3 grid(GRIDX, NB);   // 512 blocks = 2/CU exact co-residency
    k_fused<<<grid, 256, 0, stream>>>(pred, tgt, ws, out);
}

// Round 6
// 92.605 us; speedup vs baseline: 1.6524x; 1.0177x over previous
//
#include <hip/hip_runtime.h>

// Problem dims (static, match reference)
#define N_PIX (512*512)
#define NFEAT 8
#define NCLUS 8
#define NB    4
#define GRIDX 128                 // blocks per sample; 512 blocks total = 2/CU
#define NBLOCKS (GRIDX*NB)        // 512
#define NCHUNK (N_PIX/4)          // 65536 float4/int4 chunks per sample
#define STRIDE (GRIDX*256)        // 32768 -> compile-time 2 iterations/thread
#define NITER  (NCHUNK/STRIDE)    // 2
// Workspace layout (floats) — round-0 layout restored:
//   P[e][b][r] at e*512 + b*128 + r,  e in [0,72): 64 sums (f*8+c) + 8 counts
#define PART_TOTAL (72*NB*GRIDX)          // 36864
#define DIST_OFF  PART_TOTAL              // 512 per-block dist partials (packed)
#define S2_OFF    (DIST_OFF + NB*GRIDX)   // per-sample totals, stride 72
#define CTR_OFF   (S2_OFF + NB*72)        // 1 uint election counter (zeroed by K1)
// No memset node: every ws location read is written earlier in the same
// iteration (partials by K1; dist/S2/ctr by K1/K2) -> safe vs 0xAA poison.

// Lessons ledger:
//  r3: __threadfence per block per barrier (1024 L2 wb+inv) -> 99 us kernel.
//  r4: uncached scalar re-fold (4.7M coherence transactions) -> 19 MB FETCH.
//  r5: spin barrier + atomic totals + compiler remat (VGPR=76: pred NOT held
//      in regs across the barrier) -> fused kernel still ~36 us; fusion's
//      premise failed. The KERNEL BOUNDARY is the cheapest grid barrier:
//      hardware per-XCD L2 writeback/invalidate, ~3-5 us gap, no spin.
// => 2 kernels, 3 graph nodes, no software barrier, no atomics in hot path.

// Write-through / coherence-point primitives, used ONLY for the tiny
// K2-internal publication (512 dist floats + 4x72 S2 floats + 1 counter).
__device__ __forceinline__ void agent_st(float* p, float v) {
    __hip_atomic_store(p, v, __ATOMIC_RELAXED, __HIP_MEMORY_SCOPE_AGENT);
}
__device__ __forceinline__ float agent_ld(const float* p) {
    return __hip_atomic_load((float*)p, __ATOMIC_RELAXED, __HIP_MEMORY_SCOPE_AGENT);
}

// ---------------------------------------------------------------------------
// K1: per-sample per-cluster feature sums + counts (round-0 k_sums verbatim:
// select-FMA accumulation, ballot counts, 6-round reduce-scatter butterfly,
// block fold via LDS, plain transposed stores — bit-exact, absmax 0.0).
// Plus: block (0,0) zeroes the K2 election counter (replaces the memset node;
// K1->K2 kernel boundary makes it coherent).
// ---------------------------------------------------------------------------
__global__ __launch_bounds__(256) void k_sums(const float* __restrict__ pred,
                                              const int* __restrict__ tgt,
                                              float* __restrict__ ws) {
    const int tid = threadIdx.x;
    const int bx = blockIdx.x, b = blockIdx.y;
    const int lane = tid & 63, w = tid >> 6;

    if (bx == 0 && b == 0 && tid == 0)
        ((unsigned*)ws)[CTR_OFF] = 0u;   // plain store; coherent after K1 ends

    float acc[64];
#pragma unroll
    for (int i = 0; i < 64; ++i) acc[i] = 0.0f;
    int cnt[8] = {0, 0, 0, 0, 0, 0, 0, 0};

    const int4*   t4 = (const int4*)(tgt + b * N_PIX);
    const float4* p4 = (const float4*)(pred + (size_t)b * NFEAT * N_PIX);

#pragma unroll
    for (int it = 0; it < NITER; ++it) {
        const int i = bx * 256 + tid + it * STRIDE;
        int4 g4 = t4[i];
        int gs[4] = {g4.x, g4.y, g4.z, g4.w};
        float pr[NFEAT][4];
#pragma unroll
        for (int f = 0; f < NFEAT; ++f) {
            float4 v = p4[f * NCHUNK + i];
            pr[f][0] = v.x; pr[f][1] = v.y; pr[f][2] = v.z; pr[f][3] = v.w;
        }
#pragma unroll
        for (int j = 0; j < 4; ++j) {
            float m[NCLUS];
#pragma unroll
            for (int c = 0; c < NCLUS; ++c) {
                bool hit = (gs[j] == c);
                m[c] = hit ? 1.0f : 0.0f;
                cnt[c] += (int)__popcll(__ballot(hit));
            }
#pragma unroll
            for (int f = 0; f < NFEAT; ++f)
#pragma unroll
                for (int c = 0; c < NCLUS; ++c)
                    acc[f * 8 + c] = fmaf(m[c], pr[f][j], acc[f * 8 + c]);
        }
    }

    // Reduce-scatter butterfly: acc[0] = wave total of entry 'lane'.
#pragma unroll
    for (int k = 0; k < 6; ++k) {
        const int d = 1 << k;
        const int bit = (lane >> k) & 1;
#pragma unroll
        for (int p = 0; p < (64 >> 1); ++p) {
            if (p >= (64 >> (k + 1))) break;
            float a  = __shfl_xor(acc[2 * p],     d, 64);
            float vb = __shfl_xor(acc[2 * p + 1], d, 64);
            float own = bit ? acc[2 * p + 1] : acc[2 * p];
            float oth = bit ? vb : a;
            acc[p] = own + oth;
        }
    }

    __shared__ float ssum[4][64];
    __shared__ float scnt[4][8];
    ssum[w][lane] = acc[0];
    if (lane == 0) {
#pragma unroll
        for (int c = 0; c < NCLUS; ++c) scnt[w][c] = (float)cnt[c];
    }
    __syncthreads();

    if (tid < 72) {
        float s;
        if (tid < 64) s = ssum[0][tid] + ssum[1][tid] + ssum[2][tid] + ssum[3][tid];
        else { int c = tid - 64; s = scnt[0][c] + scnt[1][c] + scnt[2][c] + scnt[3][c]; }
        ws[tid * (NB * GRIDX) + b * GRIDX + bx] = s;   // transposed plain store
    }
}

// ---------------------------------------------------------------------------
// K2: round-0 k_var (cached float4 fold -> means -> distance loop, bit-exact)
// + election: each block publishes its dist partial with a write-through
// agent store (visible at the coherence point before its counter increment);
// the 512th arrival runs round-0's k_final math inline. No spin anywhere.
// ---------------------------------------------------------------------------
__global__ __launch_bounds__(256) void k_var(const float* __restrict__ pred,
                                             const int* __restrict__ tgt,
                                             float* __restrict__ ws,
                                             float* __restrict__ out) {
    __shared__ float pp[72][4];
    __shared__ float raw[72];
    __shared__ float mean[NCLUS * 9];
    __shared__ float sl[4];
    __shared__ int   is_last;
    __shared__ float sd[256];
    __shared__ float meanL[NB][64];
    __shared__ float slf[NB];
    const int tid = threadIdx.x;
    const int bx = blockIdx.x, b = blockIdx.y;
    unsigned* ctr = (unsigned*)ws + CTR_OFF;

    // Fold 72x128 partials (K1's plain stores; coherent via kernel boundary)
    // with CACHED coalesced float4 loads — association tree == round 0.
    for (int s = tid; s < 288; s += 256) {
        const int e = s >> 2, q = s & 3;
        const float4* src = (const float4*)(ws + e * (NB * GRIDX) + b * GRIDX) + q * 8;
        float4 a0 = src[0], a1 = src[1], a2 = src[2], a3 = src[3];
        float4 a4 = src[4], a5 = src[5], a6 = src[6], a7 = src[7];
        float r0 = (a0.x + a0.y + a0.z + a0.w) + (a1.x + a1.y + a1.z + a1.w);
        float r1 = (a2.x + a2.y + a2.z + a2.w) + (a3.x + a3.y + a3.z + a3.w);
        float r2 = (a4.x + a4.y + a4.z + a4.w) + (a5.x + a5.y + a5.z + a5.w);
        float r3 = (a6.x + a6.y + a6.z + a6.w) + (a7.x + a7.y + a7.z + a7.w);
        pp[e][q] = (r0 + r1) + (r2 + r3);
    }
    __syncthreads();
    if (tid < 72) {
        float s = (pp[tid][0] + pp[tid][1]) + (pp[tid][2] + pp[tid][3]);
        raw[tid] = s;
        if (bx == 0) agent_st(&ws[S2_OFF + b * 72 + tid], s);  // write-through stage
    }
    __syncthreads();   // also drains the S2 agent stores (vmcnt before barrier)
    if (tid < 64) {
        const int f = tid >> 3, c = tid & 7;
        mean[c * 9 + f] = raw[f * 8 + c] / raw[64 + c];   // stride-9: conflict-free
    }
    __syncthreads();

    const int4*   t4 = (const int4*)(tgt + b * N_PIX);
    const float4* p4 = (const float4*)(pred + (size_t)b * NFEAT * N_PIX);

    float local = 0.0f;
#pragma unroll
    for (int it = 0; it < NITER; ++it) {
        const int i = bx * 256 + tid + it * STRIDE;
        int4 g4 = t4[i];
        int gs[4] = {g4.x, g4.y, g4.z, g4.w};
        float pr[NFEAT][4];
#pragma unroll
        for (int f = 0; f < NFEAT; ++f) {
            float4 v = p4[f * NCHUNK + i];
            pr[f][0] = v.x; pr[f][1] = v.y; pr[f][2] = v.z; pr[f][3] = v.w;
        }
#pragma unroll
        for (int j = 0; j < 4; ++j) {
            const float* m = &mean[gs[j] * 9];
            float dsq = 0.0f;
#pragma unroll
            for (int f = 0; f < NFEAT; ++f) {
                float d = m[f] - pr[f][j];
                dsq = fmaf(d, d, dsq);
            }
            float diff = sqrtf(dsq);
            float dm = fminf(fmaxf(diff - 0.5f, 0.0f), 100000.0f);
            local = fmaf(dm, dm, local);
        }
    }

#pragma unroll
    for (int o = 32; o >= 1; o >>= 1) local += __shfl_xor(local, o, 64);
    if ((tid & 63) == 0) sl[tid >> 6] = local;
    __syncthreads();

    // Publish dist partial (write-through) then elect: 512th arrival finishes.
    if (tid == 0) {
        agent_st(&ws[DIST_OFF + bx * NB + b], sl[0] + sl[1] + sl[2] + sl[3]);
        asm volatile("s_waitcnt vmcnt(0)" ::: "memory");  // drain before counting
        unsigned old = __hip_atomic_fetch_add(ctr, 1u, __ATOMIC_RELAXED,
                                              __HIP_MEMORY_SCOPE_AGENT);
        is_last = (old == (unsigned)(NBLOCKS - 1));
    }
    __syncthreads();
    if (!is_last) return;

    // ---- Phase C (round-0 k_final math, executed by the last block) -------
    sd[tid] = agent_ld(ws + DIST_OFF + tid) + agent_ld(ws + DIST_OFF + 256 + tid);
    __syncthreads();
#pragma unroll
    for (int off = 128; off >= 4; off >>= 1) {
        if (tid < off) sd[tid] += sd[tid + off];
        __syncthreads();
    }
    // sd[0..3] = per-sample dist totals (index mod 4 == b preserved)

    const int bb = tid >> 6, idx = tid & 63;
    const float* S2 = ws + S2_OFF + bb * 72;
    meanL[bb][idx] = agent_ld(S2 + idx) / agent_ld(S2 + 64 + (idx & 7));
    __syncthreads();

    const int ii = idx >> 3, jj = idx & 7;
    float pdsq = 0.0f;
#pragma unroll
    for (int f = 0; f < 8; ++f) {
        float d = meanL[bb][f * 8 + ii] - meanL[bb][f * 8 + jj];
        pdsq = fmaf(d, d, pdsq);
    }
    float nrm = sqrtf(pdsq);
    float t = fminf(fmaxf(3.0f - nrm, 0.0f), 100000.0f);   // margin = 2*delta_d
    float val = (ii == jj) ? 0.0f : t * t * (1.0f / 56.0f); // / (C*(C-1))

    if (ii == 0) {
        float rsq = 0.0f;
#pragma unroll
        for (int f = 0; f < 8; ++f) {
            float m2 = meanL[bb][f * 8 + jj];
            rsq = fmaf(m2, m2, rsq);
        }
        float invc = 1.0f / agent_ld(S2 + 64 + jj);
        val += 0.001f * sqrtf(rsq) * 0.125f + sd[bb] * invc * 0.125f;
    }

#pragma unroll
    for (int o = 32; o >= 1; o >>= 1) val += __shfl_xor(val, o, 64);
    if (idx == 0) slf[bb] = val;
    __syncthreads();
    if (tid == 0) out[0] = (slf[0] + slf[1] + slf[2] + slf[3]) * 0.25f;
}

// ---------------------------------------------------------------------------
extern "C" void kernel_launch(void* const* d_in, const int* in_sizes, int n_in,
                              void* d_out, int out_size, void* d_ws, size_t ws_size,
                              hipStream_t stream) {
    const float* pred = (const float*)d_in[0];
    const int*   tgt  = (const int*)d_in[1];
    float* out = (float*)d_out;
    float* ws  = (float*)d_ws;

    dim3 grid(GRIDX, NB);   // 512 blocks
    k_sums<<<grid, 256, 0, stream>>>(pred, tgt, ws);
    k_var <<<grid, 256, 0, stream>>>(pred, tgt, ws, out);
}